// Round 1
// baseline (6194.836 us; speedup 1.0000x reference)
//
#include <hip/hip_runtime.h>
#include <math.h>

#define PI_F 3.14159265358979323846f

__device__ __forceinline__ float lrelu_f(float x){ return x >= 0.f ? x : 0.05f*x; }

// ---------------------------------------------------------------------------
// Index map: xu flat index -> lat*W + lon  (pure-gather form of grid_sample)
// xu is the C-order reshape of (H_out, W_out, Kh, Kw):
//   flat = oh*(Wo*9) + ow*9 + kh*3 + kw
// ---------------------------------------------------------------------------
__global__ void k_idxmap(int* __restrict__ map, int H, int W, int Wo, int total)
{
    int i = blockIdx.x*blockDim.x + threadIdx.x;
    if (i >= total) return;
    int oh  = i / (Wo*9);
    int rem = i % (Wo*9);
    int ow  = rem / 9;
    int r2  = rem % 9;
    int kh  = r2/3, kw = r2%3;
    int ihc = min(oh*2, H-1);
    int lat = min(max(ihc + kh - 1, 0), H-1);
    float phi = ((float)lat + 0.5f)/(float)H * PI_F - 0.5f*PI_F;
    float ca  = fmaxf(fabsf(cosf(phi)), 1e-3f);
    float d   = fminf(0.8f/ca, 4.0f);
    float jw  = (float)((ow*2) % W);
    float lonf = rintf(jw + d*(float)(kw-1));   // np.round = half-to-even
    int lon = (int)lonf % W; if (lon < 0) lon += W;
    map[i] = lat*W + lon;
}

// ---------------------------------------------------------------------------
// Fold avg_pool3(conv3x3(.)) into an effective 5x5 stride-3 kernel:
//   W5[u][v] = (1/9) * sum_{p,q in [0,2], u-p in [0,2], v-q in [0,2]} w[p][q]
// Stored TRANSPOSED: w5t[(ci*25 + u*5+v)*CO + co] for coalesced lane loads.
// ---------------------------------------------------------------------------
__global__ void k_w5(const float* __restrict__ w3, float* __restrict__ w5t, int CO, int CI)
{
    int i = blockIdx.x*blockDim.x + threadIdx.x;
    if (i >= CO*CI*25) return;
    int v = i % 5, u = (i/5) % 5;
    int cc = i / 25;                 // cc = co*CI + ci (OIHW order)
    int ci = cc % CI, co = cc / CI;
    const float* w = w3 + cc*9;
    int p0 = max(0, u-2), p1 = min(2, u);
    int q0 = max(0, v-2), q1 = min(2, v);
    float s = 0.f;
    for (int p=p0;p<=p1;++p)
        for (int q=q0;q<=q1;++q) s += w[p*3+q];
    w5t[(ci*25 + u*5 + v)*CO + co] = s*(1.0f/9.0f);
}

// transpose OIHW -> [ci*KH*KW][CO] for coalesced weight loads
__global__ void k_wT(const float* __restrict__ w, float* __restrict__ wt, int CO, int CIK)
{
    int i = blockIdx.x*blockDim.x + threadIdx.x;
    if (i >= CO*CIK) return;
    int co = i / CIK, j = i % CIK;
    wt[j*CO + co] = w[i];
}

// ---------------------------------------------------------------------------
// Fused sphere-conv: gather -> 5x5 stride-3 conv -> BN -> lrelu
// One block per (b, oh). Gathered slab (5 rows of xu, all cols) in LDS.
// Thread = (co-pair, ow-quad); weights in registers, rows via float4 LDS.
// ---------------------------------------------------------------------------
template<int CI,int CO,int OH,int OW,int RW,int IPLANE>
__global__ __launch_bounds__(256) void k_sconv(
    const float* __restrict__ in, const int* __restrict__ map,
    const float* __restrict__ w5t,
    const float* __restrict__ bg, const float* __restrict__ bb,
    const float* __restrict__ bm, const float* __restrict__ bv,
    float* __restrict__ out)
{
    constexpr int NCP = CO/2;
    constexpr int NQ  = (OW+3)/4;
    static_assert(NCP*NQ == 256, "thread mapping must cover block exactly");
    __shared__ __align__(16) float sx[CI*5*RW + 16];

    int b  = blockIdx.x / OH;
    int oh = blockIdx.x % OH;
    int tid = threadIdx.x;
    const float* xb = in + (size_t)b*CI*IPLANE;
    int r0 = oh*3;
    for (int i = tid; i < CI*5*RW; i += 256){
        int c  = i % RW;
        int t  = i / RW;
        int rr = t % 5;
        int ci = t / 5;
        int m  = map[(r0+rr)*RW + c];
        sx[(ci*5+rr)*RW + c] = xb[(size_t)ci*IPLANE + m];
    }
    __syncthreads();

    int cp  = tid % NCP;
    int q   = tid / NCP;
    int co0 = cp*2;
    int ow0 = q*4;
    float acc[2][4] = {{0.f,0.f,0.f,0.f},{0.f,0.f,0.f,0.f}};
    for (int ci=0; ci<CI; ++ci){
        float wa[25], wb2[25];
        #pragma unroll
        for (int j=0;j<25;++j){
            float2 w2 = *reinterpret_cast<const float2*>(w5t + (ci*25+j)*CO + co0);
            wa[j] = w2.x; wb2[j] = w2.y;
        }
        #pragma unroll
        for (int u=0;u<5;++u){
            const float* row = &sx[(ci*5+u)*RW + ow0*3];
            float4 a0 = *reinterpret_cast<const float4*>(row);
            float4 a1 = *reinterpret_cast<const float4*>(row+4);
            float4 a2 = *reinterpret_cast<const float4*>(row+8);
            float4 a3 = *reinterpret_cast<const float4*>(row+12);
            float rv[16] = {a0.x,a0.y,a0.z,a0.w, a1.x,a1.y,a1.z,a1.w,
                            a2.x,a2.y,a2.z,a2.w, a3.x,a3.y,a3.z,a3.w};
            #pragma unroll
            for (int k=0;k<4;++k){
                #pragma unroll
                for (int vi=0; vi<5; ++vi){
                    float s = rv[k*3+vi];
                    acc[0][k] = fmaf(s, wa[u*5+vi],  acc[0][k]);
                    acc[1][k] = fmaf(s, wb2[u*5+vi], acc[1][k]);
                }
            }
        }
    }
    #pragma unroll
    for (int j=0;j<2;++j){
        int co = co0 + j;
        float inv = bg[co]*rsqrtf(bv[co] + 1e-5f);
        float sh  = bb[co] - bm[co]*inv;
        #pragma unroll
        for (int k=0;k<4;++k){
            int ow = ow0 + k;
            if (ow < OW)
                out[((size_t)b*CO + co)*(OH*OW) + oh*OW + ow] = lrelu_f(fmaf(acc[j][k], inv, sh));
        }
    }
}

// ---------------------------------------------------------------------------
// Direct VALID conv + BN + lrelu. One block per batch item; whole input
// plane staged in LDS (row-padded to IWP for aligned float4 reads).
// ---------------------------------------------------------------------------
template<int CI,int CO,int KH,int KW,int S,int IH,int IW,int IWP,int OH,int OW>
__global__ __launch_bounds__(256) void k_conv(
    const float* __restrict__ in, const float* __restrict__ wt,
    const float* __restrict__ bg, const float* __restrict__ bb,
    const float* __restrict__ bm, const float* __restrict__ bv,
    float* __restrict__ out)
{
    __shared__ __align__(16) float sx[CI*IH*IWP + 16];
    int b = blockIdx.x, tid = threadIdx.x;
    const float* ib = in + (size_t)b*CI*IH*IW;
    for (int i = tid; i < CI*IH*IW; i += 256){
        int c = i % IW;
        int t = i / IW;
        sx[t*IWP + c] = ib[i];
    }
    __syncthreads();
    constexpr int OWT = (OW+3)/4;
    constexpr int NT  = (CO/2)*OH*OWT;
    for (int t = tid; t < NT; t += 256){
        int owt = t % OWT;
        int r   = t / OWT;
        int oh  = r % OH;
        int cp  = r / OH;
        int co0 = cp*2;
        int ow0 = owt*4;
        float acc[2][4] = {{0.f,0.f,0.f,0.f},{0.f,0.f,0.f,0.f}};
        for (int ci=0; ci<CI; ++ci){
            float wa[KH*KW], wb2[KH*KW];
            #pragma unroll
            for (int j=0;j<KH*KW;++j){
                float2 w2 = *reinterpret_cast<const float2*>(wt + (ci*KH*KW + j)*CO + co0);
                wa[j] = w2.x; wb2[j] = w2.y;
            }
            #pragma unroll
            for (int p=0;p<KH;++p){
                const float* row = &sx[(ci*IH + oh*S + p)*IWP + ow0*S];
                float4 x0 = *reinterpret_cast<const float4*>(row);
                float4 x1 = *reinterpret_cast<const float4*>(row+4);
                float rv[8] = {x0.x,x0.y,x0.z,x0.w,x1.x,x1.y,x1.z,x1.w};
                #pragma unroll
                for (int k=0;k<4;++k){
                    #pragma unroll
                    for (int qq=0; qq<KW; ++qq){
                        float s = rv[k*S+qq];
                        acc[0][k] = fmaf(s, wa[p*KW+qq],  acc[0][k]);
                        acc[1][k] = fmaf(s, wb2[p*KW+qq], acc[1][k]);
                    }
                }
            }
        }
        #pragma unroll
        for (int j=0;j<2;++j){
            int co = co0+j;
            float inv = bg[co]*rsqrtf(bv[co]+1e-5f);
            float sh  = bb[co] - bm[co]*inv;
            #pragma unroll
            for (int k=0;k<4;++k){
                int ow = ow0+k;
                if (ow < OW)
                    out[((size_t)b*CO+co)*(OH*OW) + oh*OW + ow] = lrelu_f(fmaf(acc[j][k], inv, sh));
            }
        }
    }
}

// ---------------------------------------------------------------------------
// fused = lrelu(h5_flat @ proj_w.T + v @ vproj_w.T + vproj_b)
// ---------------------------------------------------------------------------
__global__ __launch_bounds__(256) void k_head(
    const float* __restrict__ h5, const float* __restrict__ vin,
    const float* __restrict__ proj_w, const float* __restrict__ vproj_w,
    const float* __restrict__ vproj_b, float* __restrict__ fused)
{
    __shared__ __align__(16) float sh[2560];
    __shared__ float sv[9];
    int b = blockIdx.x, tid = threadIdx.x;
    for (int i = tid; i < 2560; i += 256) sh[i] = h5[(size_t)b*2560 + i];
    if (tid < 9) sv[tid] = vin[b*9 + tid];
    __syncthreads();
    const float* pw = proj_w + (size_t)tid*2560;
    float acc = 0.f;
    for (int k=0;k<2560;k+=4){
        float4 s4 = *reinterpret_cast<const float4*>(sh+k);
        float4 w4 = *reinterpret_cast<const float4*>(pw+k);
        acc = fmaf(s4.x,w4.x, fmaf(s4.y,w4.y, fmaf(s4.z,w4.z, fmaf(s4.w,w4.w, acc))));
    }
    float av = 0.f;
    #pragma unroll
    for (int k=0;k<9;++k) av += sv[k]*vproj_w[tid*9+k];
    fused[b*256+tid] = lrelu_f(acc + av + vproj_b[tid]);
}

// ---------------------------------------------------------------------------
// GRU cell: 6 dot-256 per (b, j)
// ---------------------------------------------------------------------------
__global__ __launch_bounds__(256) void k_gru(
    const float* __restrict__ fused, const float* __restrict__ hx,
    const float* __restrict__ wih, const float* __restrict__ whh,
    const float* __restrict__ bih, const float* __restrict__ bhh,
    float* __restrict__ hx_new)
{
    __shared__ __align__(16) float sf[256];
    __shared__ __align__(16) float shx[256];
    int b = blockIdx.x, j = threadIdx.x;
    sf[j]  = fused[b*256+j];
    shx[j] = hx[b*256+j];
    __syncthreads();
    float ga[3], gb[3];
    #pragma unroll
    for (int gi=0; gi<3; ++gi){
        const float* wi = wih + ((size_t)gi*256 + j)*256;
        const float* wh = whh + ((size_t)gi*256 + j)*256;
        float a = 0.f, c = 0.f;
        for (int k=0;k<256;k+=4){
            float4 f4  = *reinterpret_cast<const float4*>(sf+k);
            float4 h4  = *reinterpret_cast<const float4*>(shx+k);
            float4 wi4 = *reinterpret_cast<const float4*>(wi+k);
            float4 wh4 = *reinterpret_cast<const float4*>(wh+k);
            a = fmaf(f4.x,wi4.x, fmaf(f4.y,wi4.y, fmaf(f4.z,wi4.z, fmaf(f4.w,wi4.w, a))));
            c = fmaf(h4.x,wh4.x, fmaf(h4.y,wh4.y, fmaf(h4.z,wh4.z, fmaf(h4.w,wh4.w, c))));
        }
        ga[gi] = a + bih[gi*256+j];
        gb[gi] = c + bhh[gi*256+j];
    }
    float r = 1.f/(1.f+expf(-(ga[0]+gb[0])));
    float z = 1.f/(1.f+expf(-(ga[1]+gb[1])));
    float n = tanhf(ga[2] + r*gb[2]);
    hx_new[b*256+j] = (1.f-z)*n + z*shx[j];
}

// act = lrelu(hx_new) @ fc_w.T  -> (256,4)
__global__ void k_act(const float* __restrict__ hx_new, const float* __restrict__ fc_w,
                      float* __restrict__ act)
{
    int t = blockIdx.x*blockDim.x + threadIdx.x;
    if (t >= 1024) return;
    int b = t >> 2, o = t & 3;
    const float* h = hx_new + b*256;
    const float* w = fc_w + o*256;
    float acc = 0.f;
    for (int k=0;k<256;++k) acc = fmaf(lrelu_f(h[k]), w[k], acc);
    act[t] = acc;
}

extern "C" void kernel_launch(void* const* d_in, const int* in_sizes, int n_in,
                              void* d_out, int out_size, void* d_ws, size_t ws_size,
                              hipStream_t stream)
{
    const float* x      = (const float*)d_in[0];
    const float* vin    = (const float*)d_in[1];
    const float* hx     = (const float*)d_in[2];
    const float* sc0_w  = (const float*)d_in[3];
    const float* bn0g   = (const float*)d_in[4];
    const float* bn0b   = (const float*)d_in[5];
    const float* bn0m   = (const float*)d_in[6];
    const float* bn0v   = (const float*)d_in[7];
    const float* sc1_w  = (const float*)d_in[8];
    const float* bn1g   = (const float*)d_in[9];
    const float* bn1b   = (const float*)d_in[10];
    const float* bn1m   = (const float*)d_in[11];
    const float* bn1v   = (const float*)d_in[12];
    const float* c2_w   = (const float*)d_in[13];
    const float* bn2g   = (const float*)d_in[14];
    const float* bn2b   = (const float*)d_in[15];
    const float* bn2m   = (const float*)d_in[16];
    const float* bn2v   = (const float*)d_in[17];
    const float* c3_w   = (const float*)d_in[18];
    const float* bn3g   = (const float*)d_in[19];
    const float* bn3b   = (const float*)d_in[20];
    const float* bn3m   = (const float*)d_in[21];
    const float* bn3v   = (const float*)d_in[22];
    const float* c4_w   = (const float*)d_in[23];
    const float* bn4g   = (const float*)d_in[24];
    const float* bn4b   = (const float*)d_in[25];
    const float* bn4m   = (const float*)d_in[26];
    const float* bn4v   = (const float*)d_in[27];
    const float* c5_w   = (const float*)d_in[28];
    const float* bn5g   = (const float*)d_in[29];
    const float* bn5b   = (const float*)d_in[30];
    const float* bn5m   = (const float*)d_in[31];
    const float* bn5v   = (const float*)d_in[32];
    const float* proj_w = (const float*)d_in[33];
    const float* vproj_w= (const float*)d_in[34];
    const float* vproj_b= (const float*)d_in[35];
    const float* gru_wih= (const float*)d_in[36];
    const float* gru_whh= (const float*)d_in[37];
    const float* gru_bih= (const float*)d_in[38];
    const float* gru_bhh= (const float*)d_in[39];
    const float* fc_w   = (const float*)d_in[40];

    float* W = (float*)d_ws;
    size_t off = 0;
    int*   map0 = (int*)(W + off); off += 96*192;
    int*   map1 = (int*)(W + off); off += 48*96;
    float* w5t0 = W + off; off += 32*6*25;
    float* w5t1 = W + off; off += 64*32*25;
    float* wt2  = W + off; off += 64*64*9;
    float* wt3  = W + off; off += 64*64*4;
    float* wt4  = W + off; off += 128*64*9;
    float* wt5  = W + off; off += 128*128*9;
    float* bufA = W + off; off += (size_t)256*32*31*63;   // h0 / h2 / h4 / fused
    float* bufB = W + off; off += (size_t)256*64*15*31;   // h1 / h3 / h5

    // small precompute
    k_idxmap<<<72, 256, 0, stream>>>(map0, 64, 128, 64, 96*192);
    k_idxmap<<<18, 256, 0, stream>>>(map1, 31,  63, 32, 48*96);
    k_w5<<<(32*6*25 +255)/256, 256, 0, stream>>>(sc0_w, w5t0, 32, 6);
    k_w5<<<(64*32*25+255)/256, 256, 0, stream>>>(sc1_w, w5t1, 64, 32);
    k_wT<<<(64*64*9  +255)/256, 256, 0, stream>>>(c2_w, wt2, 64,  64*9);
    k_wT<<<(64*64*4  +255)/256, 256, 0, stream>>>(c3_w, wt3, 64,  64*4);
    k_wT<<<(128*64*9 +255)/256, 256, 0, stream>>>(c4_w, wt4, 128, 64*9);
    k_wT<<<(128*128*9+255)/256, 256, 0, stream>>>(c5_w, wt5, 128, 128*9);

    // backbone
    k_sconv<6,32,31,63,192,64*128><<<256*31, 256, 0, stream>>>(x,    map0, w5t0, bn0g,bn0b,bn0m,bn0v, bufA);
    k_sconv<32,64,15,31,96,31*63><<<256*15, 256, 0, stream>>>(bufA, map1, w5t1, bn1g,bn1b,bn1m,bn1v, bufB);
    k_conv<64,64,3,3,1,15,31,32,13,29><<<256,256,0,stream>>>(bufB, wt2, bn2g,bn2b,bn2m,bn2v, bufA);
    k_conv<64,64,2,2,2,13,29,32,6,14><<<256,256,0,stream>>>(bufA, wt3, bn3g,bn3b,bn3m,bn3v, bufB);
    k_conv<64,128,3,3,1,6,14,16,4,12><<<256,256,0,stream>>>(bufB, wt4, bn4g,bn4b,bn4m,bn4v, bufA);
    k_conv<128,128,3,3,1,4,12,12,2,10><<<256,256,0,stream>>>(bufA, wt5, bn5g,bn5b,bn5m,bn5v, bufB);

    // head
    k_head<<<256,256,0,stream>>>(bufB, vin, proj_w, vproj_w, vproj_b, bufA);
    float* outp = (float*)d_out;
    k_gru<<<256,256,0,stream>>>(bufA, hx, gru_wih, gru_whh, gru_bih, gru_bhh, outp + 1024);
    k_act<<<4,256,0,stream>>>(outp + 1024, fc_w, outp);
}

// Round 2
// 6004.922 us; speedup vs baseline: 1.0316x; 1.0316x over previous
//
#include <hip/hip_runtime.h>
#include <math.h>

#define PI_F 3.14159265358979323846f

__device__ __forceinline__ float lrelu_f(float x){ return x >= 0.f ? x : 0.05f*x; }

// ---------------------------------------------------------------------------
// Index map: xu flat index -> lat*W + lon  (pure-gather form of grid_sample)
// xu is the C-order reshape of (H_out, W_out, Kh, Kw):
//   flat = oh*(Wo*9) + ow*9 + kh*3 + kw
// ---------------------------------------------------------------------------
__global__ void k_idxmap(int* __restrict__ map, int H, int W, int Wo, int total)
{
    int i = blockIdx.x*blockDim.x + threadIdx.x;
    if (i >= total) return;
    int oh  = i / (Wo*9);
    int rem = i % (Wo*9);
    int ow  = rem / 9;
    int r2  = rem % 9;
    int kh  = r2/3, kw = r2%3;
    int ihc = min(oh*2, H-1);
    int lat = min(max(ihc + kh - 1, 0), H-1);
    float phi = ((float)lat + 0.5f)/(float)H * PI_F - 0.5f*PI_F;
    float ca  = fmaxf(fabsf(cosf(phi)), 1e-3f);
    float d   = fminf(0.8f/ca, 4.0f);
    float jw  = (float)((ow*2) % W);
    float lonf = rintf(jw + d*(float)(kw-1));   // np.round = half-to-even
    int lon = (int)lonf % W; if (lon < 0) lon += W;
    map[i] = lat*W + lon;
}

// ---------------------------------------------------------------------------
// Fold avg_pool3(conv3x3(.)) into an effective 5x5 stride-3 kernel:
//   W5[u][v] = (1/9) * sum_{p,q in [0,2], u-p in [0,2], v-q in [0,2]} w[p][q]
// Stored TRANSPOSED: w5t[(ci*25 + u*5+v)*CO + co] for coalesced lane loads.
// ---------------------------------------------------------------------------
__global__ void k_w5(const float* __restrict__ w3, float* __restrict__ w5t, int CO, int CI)
{
    int i = blockIdx.x*blockDim.x + threadIdx.x;
    if (i >= CO*CI*25) return;
    int v = i % 5, u = (i/5) % 5;
    int cc = i / 25;                 // cc = co*CI + ci (OIHW order)
    int ci = cc % CI, co = cc / CI;
    const float* w = w3 + cc*9;
    int p0 = max(0, u-2), p1 = min(2, u);
    int q0 = max(0, v-2), q1 = min(2, v);
    float s = 0.f;
    for (int p=p0;p<=p1;++p)
        for (int q=q0;q<=q1;++q) s += w[p*3+q];
    w5t[(ci*25 + u*5 + v)*CO + co] = s*(1.0f/9.0f);
}

// transpose OIHW -> [ci*KH*KW][CO] for coalesced weight loads
__global__ void k_wT(const float* __restrict__ w, float* __restrict__ wt, int CO, int CIK)
{
    int i = blockIdx.x*blockDim.x + threadIdx.x;
    if (i >= CO*CIK) return;
    int co = i / CIK, j = i % CIK;
    wt[j*CO + co] = w[i];
}

// ---------------------------------------------------------------------------
// Fused sphere-conv: gather -> 5x5 stride-3 conv -> BN -> lrelu
// One block per (b, oh). Gathered slab (5 rows of xu, all cols) in LDS.
// Thread = (co-pair, ow-quad); weights in registers, rows via float4 LDS.
// ---------------------------------------------------------------------------
template<int CI,int CO,int OH,int OW,int RW,int IPLANE>
__global__ __launch_bounds__(256) void k_sconv(
    const float* __restrict__ in, const int* __restrict__ map,
    const float* __restrict__ w5t,
    const float* __restrict__ bg, const float* __restrict__ bb,
    const float* __restrict__ bm, const float* __restrict__ bv,
    float* __restrict__ out)
{
    constexpr int NCP = CO/2;
    constexpr int NQ  = (OW+3)/4;
    static_assert(NCP*NQ == 256, "thread mapping must cover block exactly");
    __shared__ __align__(16) float sx[CI*5*RW + 16];

    int b  = blockIdx.x / OH;
    int oh = blockIdx.x % OH;
    int tid = threadIdx.x;
    const float* xb = in + (size_t)b*CI*IPLANE;
    int r0 = oh*3;
    for (int i = tid; i < CI*5*RW; i += 256){
        int c  = i % RW;
        int t  = i / RW;
        int rr = t % 5;
        int ci = t / 5;
        int m  = map[(r0+rr)*RW + c];
        sx[(ci*5+rr)*RW + c] = xb[(size_t)ci*IPLANE + m];
    }
    __syncthreads();

    int cp  = tid % NCP;
    int q   = tid / NCP;
    int co0 = cp*2;
    int ow0 = q*4;
    float acc[2][4] = {{0.f,0.f,0.f,0.f},{0.f,0.f,0.f,0.f}};
    for (int ci=0; ci<CI; ++ci){
        float wa[25], wb2[25];
        #pragma unroll
        for (int j=0;j<25;++j){
            float2 w2 = *reinterpret_cast<const float2*>(w5t + (ci*25+j)*CO + co0);
            wa[j] = w2.x; wb2[j] = w2.y;
        }
        #pragma unroll
        for (int u=0;u<5;++u){
            const float* row = &sx[(ci*5+u)*RW + ow0*3];
            float4 a0 = *reinterpret_cast<const float4*>(row);
            float4 a1 = *reinterpret_cast<const float4*>(row+4);
            float4 a2 = *reinterpret_cast<const float4*>(row+8);
            float4 a3 = *reinterpret_cast<const float4*>(row+12);
            float rv[16] = {a0.x,a0.y,a0.z,a0.w, a1.x,a1.y,a1.z,a1.w,
                            a2.x,a2.y,a2.z,a2.w, a3.x,a3.y,a3.z,a3.w};
            #pragma unroll
            for (int k=0;k<4;++k){
                #pragma unroll
                for (int vi=0; vi<5; ++vi){
                    float s = rv[k*3+vi];
                    acc[0][k] = fmaf(s, wa[u*5+vi],  acc[0][k]);
                    acc[1][k] = fmaf(s, wb2[u*5+vi], acc[1][k]);
                }
            }
        }
    }
    #pragma unroll
    for (int j=0;j<2;++j){
        int co = co0 + j;
        float inv = bg[co]*rsqrtf(bv[co] + 1e-5f);
        float sh  = bb[co] - bm[co]*inv;
        #pragma unroll
        for (int k=0;k<4;++k){
            int ow = ow0 + k;
            if (ow < OW)
                out[((size_t)b*CO + co)*(OH*OW) + oh*OW + ow] = lrelu_f(fmaf(acc[j][k], inv, sh));
        }
    }
}

// ---------------------------------------------------------------------------
// Direct VALID conv + BN + lrelu. One block per batch item; whole input
// plane staged in LDS (row-padded to IWP for aligned float4 reads).
// ---------------------------------------------------------------------------
template<int CI,int CO,int KH,int KW,int S,int IH,int IW,int IWP,int OH,int OW>
__global__ __launch_bounds__(256) void k_conv(
    const float* __restrict__ in, const float* __restrict__ wt,
    const float* __restrict__ bg, const float* __restrict__ bb,
    const float* __restrict__ bm, const float* __restrict__ bv,
    float* __restrict__ out)
{
    __shared__ __align__(16) float sx[CI*IH*IWP + 16];
    int b = blockIdx.x, tid = threadIdx.x;
    const float* ib = in + (size_t)b*CI*IH*IW;
    for (int i = tid; i < CI*IH*IW; i += 256){
        int c = i % IW;
        int t = i / IW;
        sx[t*IWP + c] = ib[i];
    }
    __syncthreads();
    constexpr int OWT = (OW+3)/4;
    constexpr int NT  = (CO/2)*OH*OWT;
    for (int t = tid; t < NT; t += 256){
        int owt = t % OWT;
        int r   = t / OWT;
        int oh  = r % OH;
        int cp  = r / OH;
        int co0 = cp*2;
        int ow0 = owt*4;
        float acc[2][4] = {{0.f,0.f,0.f,0.f},{0.f,0.f,0.f,0.f}};
        for (int ci=0; ci<CI; ++ci){
            float wa[KH*KW], wb2[KH*KW];
            #pragma unroll
            for (int j=0;j<KH*KW;++j){
                float2 w2 = *reinterpret_cast<const float2*>(wt + (ci*KH*KW + j)*CO + co0);
                wa[j] = w2.x; wb2[j] = w2.y;
            }
            #pragma unroll
            for (int p=0;p<KH;++p){
                const float* row = &sx[(ci*IH + oh*S + p)*IWP + ow0*S];
                float4 x0 = *reinterpret_cast<const float4*>(row);
                float4 x1 = *reinterpret_cast<const float4*>(row+4);
                float rv[8] = {x0.x,x0.y,x0.z,x0.w,x1.x,x1.y,x1.z,x1.w};
                #pragma unroll
                for (int k=0;k<4;++k){
                    #pragma unroll
                    for (int qq=0; qq<KW; ++qq){
                        float s = rv[k*S+qq];
                        acc[0][k] = fmaf(s, wa[p*KW+qq],  acc[0][k]);
                        acc[1][k] = fmaf(s, wb2[p*KW+qq], acc[1][k]);
                    }
                }
            }
        }
        #pragma unroll
        for (int j=0;j<2;++j){
            int co = co0+j;
            float inv = bg[co]*rsqrtf(bv[co]+1e-5f);
            float sh  = bb[co] - bm[co]*inv;
            #pragma unroll
            for (int k=0;k<4;++k){
                int ow = ow0+k;
                if (ow < OW)
                    out[((size_t)b*CO+co)*(OH*OW) + oh*OW + ow] = lrelu_f(fmaf(acc[j][k], inv, sh));
            }
        }
    }
}

// ---------------------------------------------------------------------------
// fused = lrelu(h5_flat @ proj_w.T + v @ vproj_w.T + vproj_b)
// ---------------------------------------------------------------------------
__global__ __launch_bounds__(256) void k_head(
    const float* __restrict__ h5, const float* __restrict__ vin,
    const float* __restrict__ proj_w, const float* __restrict__ vproj_w,
    const float* __restrict__ vproj_b, float* __restrict__ fused)
{
    __shared__ __align__(16) float sh[2560];
    __shared__ float sv[9];
    int b = blockIdx.x, tid = threadIdx.x;
    for (int i = tid; i < 2560; i += 256) sh[i] = h5[(size_t)b*2560 + i];
    if (tid < 9) sv[tid] = vin[b*9 + tid];
    __syncthreads();
    const float* pw = proj_w + (size_t)tid*2560;
    float acc = 0.f;
    for (int k=0;k<2560;k+=4){
        float4 s4 = *reinterpret_cast<const float4*>(sh+k);
        float4 w4 = *reinterpret_cast<const float4*>(pw+k);
        acc = fmaf(s4.x,w4.x, fmaf(s4.y,w4.y, fmaf(s4.z,w4.z, fmaf(s4.w,w4.w, acc))));
    }
    float av = 0.f;
    #pragma unroll
    for (int k=0;k<9;++k) av += sv[k]*vproj_w[tid*9+k];
    fused[b*256+tid] = lrelu_f(acc + av + vproj_b[tid]);
}

// ---------------------------------------------------------------------------
// GRU cell: 6 dot-256 per (b, j)
// ---------------------------------------------------------------------------
__global__ __launch_bounds__(256) void k_gru(
    const float* __restrict__ fused, const float* __restrict__ hx,
    const float* __restrict__ wih, const float* __restrict__ whh,
    const float* __restrict__ bih, const float* __restrict__ bhh,
    float* __restrict__ hx_new)
{
    __shared__ __align__(16) float sf[256];
    __shared__ __align__(16) float shx[256];
    int b = blockIdx.x, j = threadIdx.x;
    sf[j]  = fused[b*256+j];
    shx[j] = hx[b*256+j];
    __syncthreads();
    float ga[3], gb[3];
    #pragma unroll
    for (int gi=0; gi<3; ++gi){
        const float* wi = wih + ((size_t)gi*256 + j)*256;
        const float* wh = whh + ((size_t)gi*256 + j)*256;
        float a = 0.f, c = 0.f;
        for (int k=0;k<256;k+=4){
            float4 f4  = *reinterpret_cast<const float4*>(sf+k);
            float4 h4  = *reinterpret_cast<const float4*>(shx+k);
            float4 wi4 = *reinterpret_cast<const float4*>(wi+k);
            float4 wh4 = *reinterpret_cast<const float4*>(wh+k);
            a = fmaf(f4.x,wi4.x, fmaf(f4.y,wi4.y, fmaf(f4.z,wi4.z, fmaf(f4.w,wi4.w, a))));
            c = fmaf(h4.x,wh4.x, fmaf(h4.y,wh4.y, fmaf(h4.z,wh4.z, fmaf(h4.w,wh4.w, c))));
        }
        ga[gi] = a + bih[gi*256+j];
        gb[gi] = c + bhh[gi*256+j];
    }
    float r = 1.f/(1.f+expf(-(ga[0]+gb[0])));
    float z = 1.f/(1.f+expf(-(ga[1]+gb[1])));
    float n = tanhf(ga[2] + r*gb[2]);
    hx_new[b*256+j] = (1.f-z)*n + z*shx[j];
}

// act = lrelu(hx_new) @ fc_w.T  -> (256,4)
__global__ void k_act(const float* __restrict__ hx_new, const float* __restrict__ fc_w,
                      float* __restrict__ act)
{
    int t = blockIdx.x*blockDim.x + threadIdx.x;
    if (t >= 1024) return;
    int b = t >> 2, o = t & 3;
    const float* h = hx_new + b*256;
    const float* w = fc_w + o*256;
    float acc = 0.f;
    for (int k=0;k<256;++k) acc = fmaf(lrelu_f(h[k]), w[k], acc);
    act[t] = acc;
}

extern "C" void kernel_launch(void* const* d_in, const int* in_sizes, int n_in,
                              void* d_out, int out_size, void* d_ws, size_t ws_size,
                              hipStream_t stream)
{
    const float* x      = (const float*)d_in[0];
    const float* vin    = (const float*)d_in[1];
    const float* hx     = (const float*)d_in[2];
    const float* sc0_w  = (const float*)d_in[3];
    const float* bn0g   = (const float*)d_in[4];
    const float* bn0b   = (const float*)d_in[5];
    const float* bn0m   = (const float*)d_in[6];
    const float* bn0v   = (const float*)d_in[7];
    const float* sc1_w  = (const float*)d_in[8];
    const float* bn1g   = (const float*)d_in[9];
    const float* bn1b   = (const float*)d_in[10];
    const float* bn1m   = (const float*)d_in[11];
    const float* bn1v   = (const float*)d_in[12];
    const float* c2_w   = (const float*)d_in[13];
    const float* bn2g   = (const float*)d_in[14];
    const float* bn2b   = (const float*)d_in[15];
    const float* bn2m   = (const float*)d_in[16];
    const float* bn2v   = (const float*)d_in[17];
    const float* c3_w   = (const float*)d_in[18];
    const float* bn3g   = (const float*)d_in[19];
    const float* bn3b   = (const float*)d_in[20];
    const float* bn3m   = (const float*)d_in[21];
    const float* bn3v   = (const float*)d_in[22];
    const float* c4_w   = (const float*)d_in[23];
    const float* bn4g   = (const float*)d_in[24];
    const float* bn4b   = (const float*)d_in[25];
    const float* bn4m   = (const float*)d_in[26];
    const float* bn4v   = (const float*)d_in[27];
    const float* c5_w   = (const float*)d_in[28];
    const float* bn5g   = (const float*)d_in[29];
    const float* bn5b   = (const float*)d_in[30];
    const float* bn5m   = (const float*)d_in[31];
    const float* bn5v   = (const float*)d_in[32];
    const float* proj_w = (const float*)d_in[33];
    const float* vproj_w= (const float*)d_in[34];
    const float* vproj_b= (const float*)d_in[35];
    const float* gru_wih= (const float*)d_in[36];
    const float* gru_whh= (const float*)d_in[37];
    const float* gru_bih= (const float*)d_in[38];
    const float* gru_bhh= (const float*)d_in[39];
    const float* fc_w   = (const float*)d_in[40];

    float* W = (float*)d_ws;
    size_t off = 0;
    int*   map0 = (int*)(W + off); off += 96*192;
    int*   map1 = (int*)(W + off); off += 48*96;
    float* w5t0 = W + off; off += 32*6*25;
    float* w5t1 = W + off; off += 64*32*25;
    float* wt2  = W + off; off += 64*64*9;
    float* wt3  = W + off; off += 64*64*4;
    float* wt4  = W + off; off += 128*64*9;
    float* wt5  = W + off; off += 128*128*9;
    float* bufA = W + off; off += (size_t)256*32*31*63;   // h0 / h2 / h4 / fused
    float* bufB = W + off; off += (size_t)256*64*15*31;   // h1 / h3 / h5

    // small precompute
    k_idxmap<<<72, 256, 0, stream>>>(map0, 64, 128, 64, 96*192);
    k_idxmap<<<18, 256, 0, stream>>>(map1, 31,  63, 32, 48*96);
    k_w5<<<(32*6*25 +255)/256, 256, 0, stream>>>(sc0_w, w5t0, 32, 6);
    k_w5<<<(64*32*25+255)/256, 256, 0, stream>>>(sc1_w, w5t1, 64, 32);
    k_wT<<<(64*64*9  +255)/256, 256, 0, stream>>>(c2_w, wt2, 64,  64*9);
    k_wT<<<(64*64*4  +255)/256, 256, 0, stream>>>(c3_w, wt3, 64,  64*4);
    k_wT<<<(128*64*9 +255)/256, 256, 0, stream>>>(c4_w, wt4, 128, 64*9);
    k_wT<<<(128*128*9+255)/256, 256, 0, stream>>>(c5_w, wt5, 128, 128*9);

    // backbone
    k_sconv<6,32,31,63,192,64*128><<<256*31, 256, 0, stream>>>(x,    map0, w5t0, bn0g,bn0b,bn0m,bn0v, bufA);
    k_sconv<32,64,15,31,96,31*63><<<256*15, 256, 0, stream>>>(bufA, map1, w5t1, bn1g,bn1b,bn1m,bn1v, bufB);
    k_conv<64,64,3,3,1,15,31,32,13,29><<<256,256,0,stream>>>(bufB, wt2, bn2g,bn2b,bn2m,bn2v, bufA);
    k_conv<64,64,2,2,2,13,29,32,6,14><<<256,256,0,stream>>>(bufA, wt3, bn3g,bn3b,bn3m,bn3v, bufB);
    k_conv<64,128,3,3,1,6,14,16,4,12><<<256,256,0,stream>>>(bufB, wt4, bn4g,bn4b,bn4m,bn4v, bufA);
    k_conv<128,128,3,3,1,4,12,12,2,10><<<256,256,0,stream>>>(bufA, wt5, bn5g,bn5b,bn5m,bn5v, bufB);

    // head
    k_head<<<256,256,0,stream>>>(bufB, vin, proj_w, vproj_w, vproj_b, bufA);
    float* outp = (float*)d_out;
    k_gru<<<256,256,0,stream>>>(bufA, hx, gru_wih, gru_whh, gru_bih, gru_bhh, outp + 1024);
    k_act<<<4,256,0,stream>>>(outp + 1024, fc_w, outp);
}